// Round 1
// baseline (210.837 us; speedup 1.0000x reference)
//
#include <hip/hip_runtime.h>
#include <math.h>

#define S 16
#define C 8
#define NB 64   // batch
#define L 4096
#define K 64    // chunks per batch
#define LC 64   // steps per chunk

#define SLOT 324  // bf16 elems per matrix slot = 648 B (162 banks % 32 == 2 -> quad-distinct slot bases)
#define RS 20     // row stride in elems (40 B -> conflict-free row-major scatters)

typedef __attribute__((ext_vector_type(8))) short bf16x8;
typedef __attribute__((ext_vector_type(4))) short bf16x4;
typedef __attribute__((ext_vector_type(4))) float f32x4;
typedef unsigned long long ull;

// ws byte layout:
#define WS_INIT 0       // f32[16]
#define WS_ACC  64      // f32[16]
#define WS_CNT  128     // int[64] per-batch last-block counters (zeroed by prep each call)
#define WS_CLOG 512     // f32[4096] (16 KB)
#define WS_TTT  16896   // bf16 TTT[(p*16+n)][cc'=64] (32 KB), B-frag-ready
#define WS_CP   49664   // bf16 chunkP[4096][256]; even chunk row-major, odd [col][row]

__device__ __forceinline__ float hsig(float x) {
    return x / (1.0f + fabsf(x)) * 0.5f + 0.5f;
}
__device__ __forceinline__ unsigned short f2bf(float f) {
    unsigned int u = __float_as_uint(f);
    return (unsigned short)((u + 0x7fffu + ((u >> 16) & 1u)) >> 16);
}

// 16x16x16 bf16 MFMA. Fallback: zero-extend BOTH operands with the SAME
// K-permutation (k' = quad*8 + j <-> k = quad*4 + j, j<4) into the x32 op —
// products over dead k' are 0*0, so the result is exactly the x16 product.
__device__ __forceinline__ f32x4 mfma16(bf16x4 a, bf16x4 b, f32x4 c) {
#if __has_builtin(__builtin_amdgcn_mfma_f32_16x16x16bf16_1k)
    return __builtin_amdgcn_mfma_f32_16x16x16bf16_1k(a, b, c, 0, 0, 0);
#else
    bf16x8 a8 = {a[0], a[1], a[2], a[3], 0, 0, 0, 0};
    bf16x8 b8 = {b[0], b[1], b[2], b[3], 0, 0, 0, 0};
    return __builtin_amdgcn_mfma_f32_16x16x32_bf16(a8, b8, c, 0, 0, 0);
#endif
}

// A-frag from a row-major RS-stride slot, or B-frag from a col-major slot:
// both are elems [col*RS + quad*4 .. +3]. 8 B aligned (RS*2=40, SLOT*2=648).
__device__ __forceinline__ bf16x4 ldfrag4(const unsigned short* base, int lane) {
    return *(const bf16x4*)(base + (lane & 15) * RS + (lane >> 4) * 4);
}
// Same from a packed global 16x16 matrix (stride 16).
__device__ __forceinline__ bf16x4 ldfrag_g4(const unsigned short* base, int lane) {
    return *(const bf16x4*)(base + (lane & 15) * 16 + (lane >> 4) * 4);
}
// D-fragment -> B-fragment is the identity lane mapping for 16x16 shapes:
// D reg r = D[quad*4+r][col], B reg j = B[quad*4+j][col]. Just convert.
__device__ __forceinline__ bf16x4 cvt4(f32x4 d) {
    bf16x4 r;
    r[0] = (short)f2bf(d[0]); r[1] = (short)f2bf(d[1]);
    r[2] = (short)f2bf(d[2]); r[3] = (short)f2bf(d[3]);
    return r;
}
__device__ __forceinline__ void store16(unsigned short* slot, f32x4 d, int lane, bool odd) {
    int col = lane & 15, quad = lane >> 4;
    if (odd) {  // col-major (B-ready): packed 8 B store
        ull pk = (ull)f2bf(d[0]) | ((ull)f2bf(d[1]) << 16)
               | ((ull)f2bf(d[2]) << 32) | ((ull)f2bf(d[3]) << 48);
        *(ull*)(slot + col * RS + quad * 4) = pk;
    } else {    // row-major (A-ready): 4-elem scatter
#pragma unroll
        for (int r = 0; r < 4; r++) slot[(quad * 4 + r) * RS + col] = f2bf(d[r]);
    }
}

// lv2..root of a 32->1 tree given: lv1 even results row-major in LDS at slots
// 8w and 8w+4, lv1 odd results in registers (B1a = child of lv2 prod 2w,
// B1b = child of lv2 prod 2w+1). All B-children reg-fed (D==B layout);
// only A-children (transpose needed) round-trip LDS. Barrier-free until lv4.
__device__ __forceinline__ f32x4 tree_upper(unsigned short* slots, int lane, int w,
                                            bf16x4 B1a, bf16x4 B1b) {
    f32x4 z = {0.f, 0.f, 0.f, 0.f};
    f32x4 dA = mfma16(ldfrag4(slots + (8 * w) * SLOT, lane), B1a, z);   // lv2 prod 2w
    store16(slots + (8 * w) * SLOT, dA, lane, false);                   // -> A of lv3
    f32x4 dB = mfma16(ldfrag4(slots + (8 * w + 4) * SLOT, lane), B1b, z); // lv2 prod 2w+1
    bf16x4 B2 = cvt4(dB);                                               // -> B of lv3 (regs)
    f32x4 d3 = mfma16(ldfrag4(slots + (8 * w) * SLOT, lane), B2, z);    // lv3 prod w
    store16(slots + (8 * w) * SLOT, d3, lane, w & 1);                   // cross-wave: parity w
    __syncthreads();
    if (w < 2) {  // lv4 prod w: A = lv3(2w) rm @slot 16w, B = lv3(2w+1) cm @slot 16w+8
        f32x4 d4 = mfma16(ldfrag4(slots + (16 * w) * SLOT, lane),
                          ldfrag4(slots + (16 * w + 8) * SLOT, lane), z);
        store16(slots + (16 * w) * SLOT, d4, lane, w & 1);  // w0: slot0 rm, w1: slot16 cm
    }
    __syncthreads();
    return mfma16(ldfrag4(slots, lane), ldfrag4(slots + 16 * SLOT, lane), z);  // root
}

// 64 blocks: every block redundantly normalizes T in LDS (cheap), then block cc
// computes TTT[.][cc] = (T_c * T_{c'}) column. Block 0 also writes init/acc and
// zeroes the per-batch counters (stream-ordered before main_kernel).
__global__ void __launch_bounds__(256) prepall_kernel(const float* __restrict__ invh_init,
                                                      const float* __restrict__ invh_T,
                                                      const float* __restrict__ invh_acc,
                                                      unsigned char* __restrict__ wsb) {
    __shared__ float Tn[2048];  // Tn[(p*8+c)*16 + n]
    int t = threadIdx.x;  // 256
    int cc = blockIdx.x, c = cc >> 3, c2 = cc & 7;
    if (t < S * C) {
        float v[S]; float s = 0.f;
#pragma unroll
        for (int n = 0; n < S; n++) { v[n] = hsig(invh_T[t * S + n]); s += v[n]; }
        float inv = 1.f / s;
#pragma unroll
        for (int n = 0; n < S; n++) Tn[t * S + n] = v[n] * inv;
    }
    __syncthreads();
    int p = t >> 4, n = t & 15;
    float a = 0.f;
#pragma unroll
    for (int k = 0; k < S; k++) a += Tn[(p * 8 + c) * 16 + k] * Tn[(k * 8 + c2) * 16 + n];
    ((unsigned short*)(wsb + WS_TTT))[t * 64 + cc] = f2bf(a);

    if (cc == 0) {
        if (t < K) ((int*)(wsb + WS_CNT))[t] = 0;
        if (t < S) {
            float s = 0.f;
#pragma unroll
            for (int k = 0; k < S; k++) s += hsig(invh_init[k]);
            ((float*)(wsb + WS_INIT))[t] = hsig(invh_init[t]) / s;
            ((float*)(wsb + WS_ACC))[t] = logf(hsig(invh_acc[t]));
        }
    }
}

// Fused chunk + per-batch reduce (last-block-done).
__global__ void __launch_bounds__(256) main_kernel(const float* __restrict__ logx,
                                                   unsigned char* __restrict__ wsb,
                                                   float* __restrict__ out) {
    __shared__ __align__(16) unsigned short slots[32 * SLOT];  // 20736 B
    __shared__ __align__(16) float xs[LC * C];                 // 2048 B normalized probs
    __shared__ float clpart[4];
    __shared__ int lastFlag;

    int tid = threadIdx.x, lane = tid & 63, w = tid >> 6;
    int col = lane & 15, quad = lane >> 4;
    int chunk = blockIdx.x, b = blockIdx.y;

    // B-frags for the pair-product construct (wave w owns p-tiles 4w..4w+3).
    const unsigned short* TTT = (const unsigned short*)(wsb + WS_TTT);
    bf16x8 bfr[4][2];
#pragma unroll
    for (int jj = 0; jj < 4; jj++) {
        int t = 4 * w + jj;
#pragma unroll
        for (int kk = 0; kk < 2; kk++)
            bfr[jj][kk] = *(const bf16x8*)(TTT + (t * 16 + col) * 64 + kk * 32 + quad * 8);
    }

    // Per-step softmax straight from global: thread tid owns channels
    // {2(tid&3), 2(tid&3)+1} of step tid>>2; 4-lane-group shuffle reduce.
    const float* xg = logx + ((size_t)b * L + (size_t)chunk * LC) * C;
    float2 v = *(const float2*)(xg + 2 * tid);   // coalesced 8 B/lane
    float m = fmaxf(v.x, v.y);
    m = fmaxf(m, __shfl_xor(m, 1));
    m = fmaxf(m, __shfl_xor(m, 2));
    float e0 = __expf(v.x - m), e1 = __expf(v.y - m);
    float s = e0 + e1;
    s += __shfl_xor(s, 1);
    s += __shfl_xor(s, 2);
    float inv = 1.0f / s;
    *(float2*)(xs + 2 * tid) = make_float2(e0 * inv, e1 * inv);  // xs[step*8 + c] == xs[2*tid]
    float lx = ((tid & 3) == 0) ? (m + __logf(s)) : 0.f;         // one contribution per step
#pragma unroll
    for (int d = 1; d < 64; d <<= 1) lx += __shfl_xor(lx, d);    // wave partial (16 steps)
    if (lane == 0) clpart[w] = lx;
    __syncthreads();
    if (tid == 0)
        ((float*)(wsb + WS_CLOG))[b * K + chunk] = clpart[0] + clpart[1] + clpart[2] + clpart[3];

    // A-frags: y[i][cc'] = xn[2i][c]*xn[2i+1][c'].
    bf16x8 afr[2][2];
#pragma unroll
    for (int mt = 0; mt < 2; mt++) {
        int i2 = 2 * (mt * 16 + col);
        const float4* x1p = (const float4*)(xs + (i2 + 1) * 8);
        float4 xa = x1p[0], xb = x1p[1];
#pragma unroll
        for (int kk = 0; kk < 2; kk++) {
            float x0 = xs[i2 * 8 + kk * 4 + quad];
            bf16x8 a;
            a[0] = (short)f2bf(x0 * xa.x); a[1] = (short)f2bf(x0 * xa.y);
            a[2] = (short)f2bf(x0 * xa.z); a[3] = (short)f2bf(x0 * xa.w);
            a[4] = (short)f2bf(x0 * xb.x); a[5] = (short)f2bf(x0 * xb.y);
            a[6] = (short)f2bf(x0 * xb.z); a[7] = (short)f2bf(x0 * xb.w);
            afr[mt][kk] = a;
        }
    }

    // Pair-product construct -> slots 0..31 (parity i&1: even rm / odd cm).
#pragma unroll
    for (int mt = 0; mt < 2; mt++)
#pragma unroll
        for (int jj = 0; jj < 4; jj++) {
            f32x4 acc = {0.f, 0.f, 0.f, 0.f};
#pragma unroll
            for (int kk = 0; kk < 2; kk++)
                acc = __builtin_amdgcn_mfma_f32_16x16x32_bf16(afr[mt][kk], bfr[jj][kk], acc, 0, 0, 0);
            int t = 4 * w + jj;  // = p
#pragma unroll
            for (int r = 0; r < 4; r++) {
                int i = mt * 16 + quad * 4 + r;
                int off = (i & 1) ? (col * RS + t) : (t * RS + col);
                slots[i * SLOT + off] = f2bf(acc[r]);
            }
        }
    __syncthreads();

    // lv1: wave w owns products i in [4w,4w+4). Even i -> LDS (A of lv2),
    // odd i -> registers (B of lv2, D==B layout).
    bf16x4 B1[2];
    {
        f32x4 z = {0.f, 0.f, 0.f, 0.f};
#pragma unroll
        for (int i2 = 0; i2 < 4; i2++) {
            int i = 4 * w + i2;
            f32x4 d = mfma16(ldfrag4(slots + (2 * i) * SLOT, lane),
                             ldfrag4(slots + (2 * i + 1) * SLOT, lane), z);
            if (i2 & 1) B1[i2 >> 1] = cvt4(d);
            else store16(slots + (2 * i) * SLOT, d, lane, false);
        }
    }
    f32x4 root = tree_upper(slots, lane, w, B1[0], B1[1]);

    if (w == 0) {
        unsigned short* cp = (unsigned short*)(wsb + WS_CP) + ((size_t)b * K + chunk) * 256;
        if (chunk & 1) {
            ull pk = (ull)f2bf(root[0]) | ((ull)f2bf(root[1]) << 16)
                   | ((ull)f2bf(root[2]) << 32) | ((ull)f2bf(root[3]) << 48);
            *(ull*)(cp + col * 16 + quad * 4) = pk;
        } else {
#pragma unroll
            for (int r = 0; r < 4; r++) cp[(quad * 4 + r) * 16 + col] = f2bf(root[r]);
        }
        __threadfence();  // release WS_CP + WS_CLOG (only wave 0 wrote globals)
    }
    __syncthreads();
    if (tid == 0) lastFlag = (atomicAdd((int*)(wsb + WS_CNT) + b, 1) == 63) ? 1 : 0;
    __syncthreads();
    if (!lastFlag) return;

    // ---- last block of batch b: reduce the 64 chunk matrices ----
    __threadfence();  // acquire: other XCDs' WS_CP/WS_CLOG writes
    const unsigned short* cpb = (const unsigned short*)(wsb + WS_CP) + (size_t)b * K * 256;
    // lv0: 32 products of global pairs (even chunk rm -> A, odd cm -> B).
    // Even results -> slot j rm; odd results -> regs (B of lv1).
    bf16x4 B0[4];
    {
        f32x4 z = {0.f, 0.f, 0.f, 0.f};
#pragma unroll
        for (int i2 = 0; i2 < 8; i2++) {
            int j = 8 * w + i2;
            f32x4 d = mfma16(ldfrag_g4(cpb + (size_t)(2 * j) * 256, lane),
                             ldfrag_g4(cpb + (size_t)(2 * j + 1) * 256, lane), z);
            if (i2 & 1) B0[i2 >> 1] = cvt4(d);
            else store16(slots + j * SLOT, d, lane, false);
        }
    }
    bf16x4 B1r[2];
    {
        f32x4 z = {0.f, 0.f, 0.f, 0.f};
#pragma unroll
        for (int i2 = 0; i2 < 4; i2++) {
            int i = 4 * w + i2;  // A = lv0 result 2i @ slot 2i (= 8w + 2*i2)
            f32x4 d = mfma16(ldfrag4(slots + (2 * i) * SLOT, lane), B0[i2], z);
            if (i2 & 1) B1r[i2 >> 1] = cvt4(d);
            else store16(slots + (2 * i) * SLOT, d, lane, false);
        }
    }
    f32x4 troot = tree_upper(slots, lane, w, B1r[0], B1r[1]);

    if (w == 0) {
        const float* initp = (const float*)(wsb + WS_INIT);
        const float* acclog = (const float*)(wsb + WS_ACC);
        float part = 0.f;
#pragma unroll
        for (int r = 0; r < 4; r++) part += initp[quad * 4 + r] * troot[r];
        part += __shfl_xor(part, 16);
        part += __shfl_xor(part, 32);
        float lp = logf(fmaxf(part, 0.f) + 1e-30f) + acclog[col];
        float mx = lp;
#pragma unroll
        for (int d = 1; d < 16; d <<= 1) mx = fmaxf(mx, __shfl_xor(mx, d));
        float a2 = isfinite(mx) ? mx : 0.0f;  // jax.nn.logsumexp semantics
        float sm = expf(lp - a2);
#pragma unroll
        for (int d = 1; d < 16; d <<= 1) sm += __shfl_xor(sm, d);
        float cl = ((const float*)(wsb + WS_CLOG))[b * K + lane];
#pragma unroll
        for (int d = 1; d < 64; d <<= 1) cl += __shfl_xor(cl, d);
        if (lane == 0) out[b] = logf(sm) + a2 + cl;
    }
}

extern "C" void kernel_launch(void* const* d_in, const int* in_sizes, int n_in,
                              void* d_out, int out_size, void* d_ws, size_t ws_size,
                              hipStream_t stream) {
    const float* logx = (const float*)d_in[0];   // (B, L, C) f32
    const float* init = (const float*)d_in[1];   // (S,) f32
    const float* T    = (const float*)d_in[2];   // (S, C, S) f32
    const float* acc  = (const float*)d_in[3];   // (S,) f32
    unsigned char* wsb = (unsigned char*)d_ws;
    float* out = (float*)d_out;

    prepall_kernel<<<64, 256, 0, stream>>>(init, T, acc, wsb);
    main_kernel<<<dim3(K, NB), 256, 0, stream>>>(logx, wsb, out);
}

// Round 2
// 85.407 us; speedup vs baseline: 2.4686x; 2.4686x over previous
//
#include <hip/hip_runtime.h>
#include <math.h>

#define S 16
#define C 8
#define NB 64   // batch
#define L 4096
#define K 64    // chunks per batch
#define LC 64   // steps per chunk

#define SLOT 324  // bf16 elems per matrix slot = 648 B (162 banks % 32 == 2 -> quad-distinct slot bases)
#define RS 20     // row stride in elems (40 B -> conflict-free row-major scatters)

typedef __attribute__((ext_vector_type(8))) short bf16x8;
typedef __attribute__((ext_vector_type(4))) short bf16x4;
typedef __attribute__((ext_vector_type(4))) float f32x4;
typedef unsigned long long ull;

// ws byte layout:
#define WS_INIT 0       // f32[16]
#define WS_ACC  64      // f32[16]
#define WS_CLOG 512     // f32[4096] (16 KB)
#define WS_TTT  16896   // bf16 TTT[(p*16+n)][cc'=64] (32 KB), B-frag-ready
#define WS_CP   49664   // bf16 chunkP[4096][256]; even chunk row-major, odd [col][row]

__device__ __forceinline__ float hsig(float x) {
    return x / (1.0f + fabsf(x)) * 0.5f + 0.5f;
}
__device__ __forceinline__ unsigned short f2bf(float f) {
    unsigned int u = __float_as_uint(f);
    return (unsigned short)((u + 0x7fffu + ((u >> 16) & 1u)) >> 16);
}

// 16x16x16 bf16 MFMA. Fallback: zero-extend BOTH operands with the SAME
// K-permutation (k' = quad*8 + j <-> k = quad*4 + j, j<4) into the x32 op —
// products over dead k' are 0*0, so the result is exactly the x16 product.
__device__ __forceinline__ f32x4 mfma16(bf16x4 a, bf16x4 b, f32x4 c) {
#if __has_builtin(__builtin_amdgcn_mfma_f32_16x16x16bf16_1k)
    return __builtin_amdgcn_mfma_f32_16x16x16bf16_1k(a, b, c, 0, 0, 0);
#else
    bf16x8 a8 = {a[0], a[1], a[2], a[3], 0, 0, 0, 0};
    bf16x8 b8 = {b[0], b[1], b[2], b[3], 0, 0, 0, 0};
    return __builtin_amdgcn_mfma_f32_16x16x32_bf16(a8, b8, c, 0, 0, 0);
#endif
}

// A-frag from a row-major RS-stride slot, or B-frag from a col-major slot:
// both are elems [col*RS + quad*4 .. +3]. 8 B aligned (RS*2=40, SLOT*2=648).
__device__ __forceinline__ bf16x4 ldfrag4(const unsigned short* base, int lane) {
    return *(const bf16x4*)(base + (lane & 15) * RS + (lane >> 4) * 4);
}
// Same from a packed global 16x16 matrix (stride 16).
__device__ __forceinline__ bf16x4 ldfrag_g4(const unsigned short* base, int lane) {
    return *(const bf16x4*)(base + (lane & 15) * 16 + (lane >> 4) * 4);
}
// D-fragment -> B-fragment is the identity lane mapping for 16x16 shapes:
// D reg r = D[quad*4+r][col], B reg j = B[quad*4+j][col]. Just convert.
__device__ __forceinline__ bf16x4 cvt4(f32x4 d) {
    bf16x4 r;
    r[0] = (short)f2bf(d[0]); r[1] = (short)f2bf(d[1]);
    r[2] = (short)f2bf(d[2]); r[3] = (short)f2bf(d[3]);
    return r;
}
__device__ __forceinline__ void store16(unsigned short* slot, f32x4 d, int lane, bool odd) {
    int col = lane & 15, quad = lane >> 4;
    if (odd) {  // col-major (B-ready): packed 8 B store
        ull pk = (ull)f2bf(d[0]) | ((ull)f2bf(d[1]) << 16)
               | ((ull)f2bf(d[2]) << 32) | ((ull)f2bf(d[3]) << 48);
        *(ull*)(slot + col * RS + quad * 4) = pk;
    } else {    // row-major (A-ready): 4-elem scatter
#pragma unroll
        for (int r = 0; r < 4; r++) slot[(quad * 4 + r) * RS + col] = f2bf(d[r]);
    }
}

// lv2..root of a 32->1 tree given: lv1 even results row-major in LDS at slots
// 8w and 8w+4, lv1 odd results in registers (B1a = child of lv2 prod 2w,
// B1b = child of lv2 prod 2w+1). All B-children reg-fed (D==B layout);
// only A-children (transpose needed) round-trip LDS. Barrier-free until lv4.
__device__ __forceinline__ f32x4 tree_upper(unsigned short* slots, int lane, int w,
                                            bf16x4 B1a, bf16x4 B1b) {
    f32x4 z = {0.f, 0.f, 0.f, 0.f};
    f32x4 dA = mfma16(ldfrag4(slots + (8 * w) * SLOT, lane), B1a, z);   // lv2 prod 2w
    store16(slots + (8 * w) * SLOT, dA, lane, false);                   // -> A of lv3
    f32x4 dB = mfma16(ldfrag4(slots + (8 * w + 4) * SLOT, lane), B1b, z); // lv2 prod 2w+1
    bf16x4 B2 = cvt4(dB);                                               // -> B of lv3 (regs)
    f32x4 d3 = mfma16(ldfrag4(slots + (8 * w) * SLOT, lane), B2, z);    // lv3 prod w
    store16(slots + (8 * w) * SLOT, d3, lane, w & 1);                   // cross-wave: parity w
    __syncthreads();
    if (w < 2) {  // lv4 prod w: A = lv3(2w) rm @slot 16w, B = lv3(2w+1) cm @slot 16w+8
        f32x4 d4 = mfma16(ldfrag4(slots + (16 * w) * SLOT, lane),
                          ldfrag4(slots + (16 * w + 8) * SLOT, lane), z);
        store16(slots + (16 * w) * SLOT, d4, lane, w & 1);  // w0: slot0 rm, w1: slot16 cm
    }
    __syncthreads();
    return mfma16(ldfrag4(slots, lane), ldfrag4(slots + 16 * SLOT, lane), z);  // root
}

// 64 blocks: every block redundantly normalizes T in LDS (cheap), then block cc
// computes TTT[.][cc] = (T_c * T_{c'}) column. Block 0 also writes init/acc.
__global__ void __launch_bounds__(256) prepall_kernel(const float* __restrict__ invh_init,
                                                      const float* __restrict__ invh_T,
                                                      const float* __restrict__ invh_acc,
                                                      unsigned char* __restrict__ wsb) {
    __shared__ float Tn[2048];  // Tn[(p*8+c)*16 + n]
    int t = threadIdx.x;  // 256
    int cc = blockIdx.x, c = cc >> 3, c2 = cc & 7;
    if (t < S * C) {
        float v[S]; float s = 0.f;
#pragma unroll
        for (int n = 0; n < S; n++) { v[n] = hsig(invh_T[t * S + n]); s += v[n]; }
        float inv = 1.f / s;
#pragma unroll
        for (int n = 0; n < S; n++) Tn[t * S + n] = v[n] * inv;
    }
    __syncthreads();
    int p = t >> 4, n = t & 15;
    float a = 0.f;
#pragma unroll
    for (int k = 0; k < S; k++) a += Tn[(p * 8 + c) * 16 + k] * Tn[(k * 8 + c2) * 16 + n];
    ((unsigned short*)(wsb + WS_TTT))[t * 64 + cc] = f2bf(a);

    if (cc == 0 && t < S) {
        float s = 0.f;
#pragma unroll
        for (int k = 0; k < S; k++) s += hsig(invh_init[k]);
        ((float*)(wsb + WS_INIT))[t] = hsig(invh_init[t]) / s;
        ((float*)(wsb + WS_ACC))[t] = logf(hsig(invh_acc[t]));
    }
}

__global__ void __launch_bounds__(256) chunk_kernel(const float* __restrict__ logx,
                                                    unsigned char* __restrict__ wsb) {
    __shared__ __align__(16) unsigned short slots[32 * SLOT];  // 20736 B
    __shared__ __align__(16) float xs[LC * C];                 // 2048 B normalized probs
    __shared__ float clpart[4];

    int tid = threadIdx.x, lane = tid & 63, w = tid >> 6;
    int col = lane & 15, quad = lane >> 4;
    int chunk = blockIdx.x, b = blockIdx.y;

    // B-frags for the pair-product construct (wave w owns p-tiles 4w..4w+3).
    const unsigned short* TTT = (const unsigned short*)(wsb + WS_TTT);
    bf16x8 bfr[4][2];
#pragma unroll
    for (int jj = 0; jj < 4; jj++) {
        int t = 4 * w + jj;
#pragma unroll
        for (int kk = 0; kk < 2; kk++)
            bfr[jj][kk] = *(const bf16x8*)(TTT + (t * 16 + col) * 64 + kk * 32 + quad * 8);
    }

    // Per-step softmax straight from global: thread tid owns channels
    // {2(tid&3), 2(tid&3)+1} of step tid>>2; 4-lane-group shuffle reduce.
    const float* xg = logx + ((size_t)b * L + (size_t)chunk * LC) * C;
    float2 v = *(const float2*)(xg + 2 * tid);   // coalesced 8 B/lane
    float m = fmaxf(v.x, v.y);
    m = fmaxf(m, __shfl_xor(m, 1));
    m = fmaxf(m, __shfl_xor(m, 2));
    float e0 = __expf(v.x - m), e1 = __expf(v.y - m);
    float s = e0 + e1;
    s += __shfl_xor(s, 1);
    s += __shfl_xor(s, 2);
    float inv = 1.0f / s;
    *(float2*)(xs + 2 * tid) = make_float2(e0 * inv, e1 * inv);  // xs[step*8 + c] == xs[2*tid]
    float lx = ((tid & 3) == 0) ? (m + __logf(s)) : 0.f;         // one contribution per step
#pragma unroll
    for (int d = 1; d < 64; d <<= 1) lx += __shfl_xor(lx, d);    // wave partial (16 steps)
    if (lane == 0) clpart[w] = lx;
    __syncthreads();
    if (tid == 0)
        ((float*)(wsb + WS_CLOG))[b * K + chunk] = clpart[0] + clpart[1] + clpart[2] + clpart[3];

    // A-frags: y[i][cc'] = xn[2i][c]*xn[2i+1][c'].
    bf16x8 afr[2][2];
#pragma unroll
    for (int mt = 0; mt < 2; mt++) {
        int i2 = 2 * (mt * 16 + col);
        const float4* x1p = (const float4*)(xs + (i2 + 1) * 8);
        float4 xa = x1p[0], xb = x1p[1];
#pragma unroll
        for (int kk = 0; kk < 2; kk++) {
            float x0 = xs[i2 * 8 + kk * 4 + quad];
            bf16x8 a;
            a[0] = (short)f2bf(x0 * xa.x); a[1] = (short)f2bf(x0 * xa.y);
            a[2] = (short)f2bf(x0 * xa.z); a[3] = (short)f2bf(x0 * xa.w);
            a[4] = (short)f2bf(x0 * xb.x); a[5] = (short)f2bf(x0 * xb.y);
            a[6] = (short)f2bf(x0 * xb.z); a[7] = (short)f2bf(x0 * xb.w);
            afr[mt][kk] = a;
        }
    }

    // Pair-product construct -> slots 0..31 (parity i&1: even rm / odd cm).
#pragma unroll
    for (int mt = 0; mt < 2; mt++)
#pragma unroll
        for (int jj = 0; jj < 4; jj++) {
            f32x4 acc = {0.f, 0.f, 0.f, 0.f};
#pragma unroll
            for (int kk = 0; kk < 2; kk++)
                acc = __builtin_amdgcn_mfma_f32_16x16x32_bf16(afr[mt][kk], bfr[jj][kk], acc, 0, 0, 0);
            int t = 4 * w + jj;  // = p
#pragma unroll
            for (int r = 0; r < 4; r++) {
                int i = mt * 16 + quad * 4 + r;
                int off = (i & 1) ? (col * RS + t) : (t * RS + col);
                slots[i * SLOT + off] = f2bf(acc[r]);
            }
        }
    __syncthreads();

    // lv1: wave w owns products i in [4w,4w+4). Even i -> LDS (A of lv2),
    // odd i -> registers (B of lv2, D==B layout).
    bf16x4 B1[2];
    {
        f32x4 z = {0.f, 0.f, 0.f, 0.f};
#pragma unroll
        for (int i2 = 0; i2 < 4; i2++) {
            int i = 4 * w + i2;
            f32x4 d = mfma16(ldfrag4(slots + (2 * i) * SLOT, lane),
                             ldfrag4(slots + (2 * i + 1) * SLOT, lane), z);
            if (i2 & 1) B1[i2 >> 1] = cvt4(d);
            else store16(slots + (2 * i) * SLOT, d, lane, false);
        }
    }
    f32x4 root = tree_upper(slots, lane, w, B1[0], B1[1]);

    if (w == 0) {
        unsigned short* cp = (unsigned short*)(wsb + WS_CP) + ((size_t)b * K + chunk) * 256;
        if (chunk & 1) {
            ull pk = (ull)f2bf(root[0]) | ((ull)f2bf(root[1]) << 16)
                   | ((ull)f2bf(root[2]) << 32) | ((ull)f2bf(root[3]) << 48);
            *(ull*)(cp + col * 16 + quad * 4) = pk;
        } else {
#pragma unroll
            for (int r = 0; r < 4; r++) cp[(quad * 4 + r) * 16 + col] = f2bf(root[r]);
        }
    }
}

__global__ void __launch_bounds__(256) reduce_kernel(unsigned char* __restrict__ wsb,
                                                     float* __restrict__ out) {
    __shared__ __align__(16) unsigned short slots[32 * SLOT];  // 20736 B
    int tid = threadIdx.x, lane = tid & 63, w = tid >> 6;
    int col = lane & 15, quad = lane >> 4;
    int b = blockIdx.x;

    const unsigned short* cpb = (const unsigned short*)(wsb + WS_CP) + (size_t)b * K * 256;
    // lv0: 32 products of global pairs (even chunk rm -> A, odd cm -> B).
    // Even results -> slot j rm; odd results -> regs (B of lv1).
    bf16x4 B0[4];
    {
        f32x4 z = {0.f, 0.f, 0.f, 0.f};
#pragma unroll
        for (int i2 = 0; i2 < 8; i2++) {
            int j = 8 * w + i2;
            f32x4 d = mfma16(ldfrag_g4(cpb + (size_t)(2 * j) * 256, lane),
                             ldfrag_g4(cpb + (size_t)(2 * j + 1) * 256, lane), z);
            if (i2 & 1) B0[i2 >> 1] = cvt4(d);
            else store16(slots + j * SLOT, d, lane, false);
        }
    }
    bf16x4 B1r[2];
    {
        f32x4 z = {0.f, 0.f, 0.f, 0.f};
#pragma unroll
        for (int i2 = 0; i2 < 4; i2++) {
            int i = 4 * w + i2;  // A = lv0 result 2i @ slot 2i (= 8w + 2*i2)
            f32x4 d = mfma16(ldfrag4(slots + (2 * i) * SLOT, lane), B0[i2], z);
            if (i2 & 1) B1r[i2 >> 1] = cvt4(d);
            else store16(slots + (2 * i) * SLOT, d, lane, false);
        }
    }
    f32x4 troot = tree_upper(slots, lane, w, B1r[0], B1r[1]);

    if (w == 0) {
        const float* initp = (const float*)(wsb + WS_INIT);
        const float* acclog = (const float*)(wsb + WS_ACC);
        float part = 0.f;
#pragma unroll
        for (int r = 0; r < 4; r++) part += initp[quad * 4 + r] * troot[r];
        part += __shfl_xor(part, 16);
        part += __shfl_xor(part, 32);
        float lp = logf(fmaxf(part, 0.f) + 1e-30f) + acclog[col];
        float mx = lp;
#pragma unroll
        for (int d = 1; d < 16; d <<= 1) mx = fmaxf(mx, __shfl_xor(mx, d));
        float a2 = isfinite(mx) ? mx : 0.0f;  // jax.nn.logsumexp semantics
        float sm = expf(lp - a2);
#pragma unroll
        for (int d = 1; d < 16; d <<= 1) sm += __shfl_xor(sm, d);
        float cl = ((const float*)(wsb + WS_CLOG))[b * K + lane];
#pragma unroll
        for (int d = 1; d < 64; d <<= 1) cl += __shfl_xor(cl, d);
        if (lane == 0) out[b] = logf(sm) + a2 + cl;
    }
}

extern "C" void kernel_launch(void* const* d_in, const int* in_sizes, int n_in,
                              void* d_out, int out_size, void* d_ws, size_t ws_size,
                              hipStream_t stream) {
    const float* logx = (const float*)d_in[0];   // (B, L, C) f32
    const float* init = (const float*)d_in[1];   // (S,) f32
    const float* T    = (const float*)d_in[2];   // (S, C, S) f32
    const float* acc  = (const float*)d_in[3];   // (S,) f32
    unsigned char* wsb = (unsigned char*)d_ws;
    float* out = (float*)d_out;

    prepall_kernel<<<64, 256, 0, stream>>>(init, T, acc, wsb);
    chunk_kernel<<<dim3(K, NB), 256, 0, stream>>>(logx, wsb);
    reduce_kernel<<<NB, 256, 0, stream>>>(wsb, out);
}

// Round 3
// 83.659 us; speedup vs baseline: 2.5202x; 1.0209x over previous
//
#include <hip/hip_runtime.h>
#include <hip/hip_bf16.h>
#include <math.h>

#define S 16
#define C 8
#define NB 64   // batch
#define L 4096
#define K 64    // chunks per batch
#define LC 64   // steps per chunk

#define SLOT 324  // bf16 elems per matrix slot = 648 B (162 banks % 32 == 2 -> quad-distinct slot bases)
#define RS 20     // row stride in elems (40 B -> conflict-free row-major scatters)
#define XSS 10    // xs floats per step (40 B stride -> 2-way-max bank aliasing on A-frag reads)

typedef __attribute__((ext_vector_type(8))) short bf16x8;
typedef __attribute__((ext_vector_type(4))) short bf16x4;
typedef __attribute__((ext_vector_type(4))) float f32x4;
typedef unsigned long long ull;

// ws byte layout:
#define WS_INIT 0       // f32[16]
#define WS_ACC  64      // f32[16]
#define WS_CLOG 512     // f32[4096] (16 KB)
#define WS_TTT  16896   // bf16 TTT[(p*16+n)][cc'=64] (32 KB), B-frag-ready
#define WS_CP   49664   // bf16 chunkP[4096][256]; even chunk row-major, odd [col][row]

__device__ __forceinline__ float hsig(float x) {
    return x / (1.0f + fabsf(x)) * 0.5f + 0.5f;
}
// Native RNE bf16 converts (v_cvt_pk_bf16_f32) — same rounding as the manual
// (u + 0x7fff + lsb) >> 16 for finite inputs, 1 VALU op instead of 3-4.
__device__ __forceinline__ unsigned int f2bf2(float a, float b) {
    __hip_bfloat162 h = __float22bfloat162_rn(make_float2(a, b));
    unsigned int u; __builtin_memcpy(&u, &h, 4); return u;
}
__device__ __forceinline__ unsigned short f2bf(float f) {
    __hip_bfloat16 h = __float2bfloat16(f);
    unsigned short u; __builtin_memcpy(&u, &h, 2); return u;
}

// 16x16x16 bf16 MFMA. Fallback: zero-extend BOTH operands with the SAME
// K-permutation into the x32 op — dead products are 0*0, result identical.
__device__ __forceinline__ f32x4 mfma16(bf16x4 a, bf16x4 b, f32x4 c) {
#if __has_builtin(__builtin_amdgcn_mfma_f32_16x16x16bf16_1k)
    return __builtin_amdgcn_mfma_f32_16x16x16bf16_1k(a, b, c, 0, 0, 0);
#else
    bf16x8 a8 = {a[0], a[1], a[2], a[3], 0, 0, 0, 0};
    bf16x8 b8 = {b[0], b[1], b[2], b[3], 0, 0, 0, 0};
    return __builtin_amdgcn_mfma_f32_16x16x32_bf16(a8, b8, c, 0, 0, 0);
#endif
}

// A-frag from a row-major RS-stride slot, or B-frag from a col-major slot:
// both are elems [col*RS + quad*4 .. +3]. 8 B aligned (RS*2=40, SLOT*2=648).
__device__ __forceinline__ bf16x4 ldfrag4(const unsigned short* base, int lane) {
    return *(const bf16x4*)(base + (lane & 15) * RS + (lane >> 4) * 4);
}
// Same from a packed global 16x16 matrix (stride 16).
__device__ __forceinline__ bf16x4 ldfrag_g4(const unsigned short* base, int lane) {
    return *(const bf16x4*)(base + (lane & 15) * 16 + (lane >> 4) * 4);
}
// D-fragment -> B-fragment is the identity lane mapping for 16x16 shapes.
__device__ __forceinline__ bf16x4 cvt4(f32x4 d) {
    union { unsigned int u[2]; bf16x4 v; } cv;
    cv.u[0] = f2bf2(d[0], d[1]);
    cv.u[1] = f2bf2(d[2], d[3]);
    return cv.v;
}
__device__ __forceinline__ void store16(unsigned short* slot, f32x4 d, int lane, bool odd) {
    int col = lane & 15, quad = lane >> 4;
    if (odd) {  // col-major (B-ready): packed 8 B store
        ull pk = (ull)f2bf2(d[0], d[1]) | ((ull)f2bf2(d[2], d[3]) << 32);
        *(ull*)(slot + col * RS + quad * 4) = pk;
    } else {    // row-major (A-ready): 4-elem scatter
#pragma unroll
        for (int r = 0; r < 4; r++) slot[(quad * 4 + r) * RS + col] = f2bf(d[r]);
    }
}

// lv2..root of a 32->1 tree; lv1 even results row-major in LDS at slots 8w and
// 8w+4, lv1 odd results reg-fed (D==B layout). Barrier-free until lv4.
__device__ __forceinline__ f32x4 tree_upper(unsigned short* slots, int lane, int w,
                                            bf16x4 B1a, bf16x4 B1b) {
    f32x4 z = {0.f, 0.f, 0.f, 0.f};
    f32x4 dA = mfma16(ldfrag4(slots + (8 * w) * SLOT, lane), B1a, z);   // lv2 prod 2w
    store16(slots + (8 * w) * SLOT, dA, lane, false);                   // -> A of lv3
    f32x4 dB = mfma16(ldfrag4(slots + (8 * w + 4) * SLOT, lane), B1b, z); // lv2 prod 2w+1
    bf16x4 B2 = cvt4(dB);                                               // -> B of lv3 (regs)
    f32x4 d3 = mfma16(ldfrag4(slots + (8 * w) * SLOT, lane), B2, z);    // lv3 prod w
    store16(slots + (8 * w) * SLOT, d3, lane, w & 1);                   // cross-wave: parity w
    __syncthreads();
    if (w < 2) {  // lv4 prod w: A = lv3(2w) rm @slot 16w, B = lv3(2w+1) cm @slot 16w+8
        f32x4 d4 = mfma16(ldfrag4(slots + (16 * w) * SLOT, lane),
                          ldfrag4(slots + (16 * w + 8) * SLOT, lane), z);
        store16(slots + (16 * w) * SLOT, d4, lane, w & 1);  // w0: slot0 rm, w1: slot16 cm
    }
    __syncthreads();
    return mfma16(ldfrag4(slots, lane), ldfrag4(slots + 16 * SLOT, lane), z);  // root
}

// 64 blocks: every block redundantly normalizes T in LDS (cheap), then block cc
// computes TTT[.][cc] = (T_c * T_{c'}) column. Block 0 also writes init/acc.
__global__ void __launch_bounds__(256) prepall_kernel(const float* __restrict__ invh_init,
                                                      const float* __restrict__ invh_T,
                                                      const float* __restrict__ invh_acc,
                                                      unsigned char* __restrict__ wsb) {
    __shared__ float Tn[2048];  // Tn[(p*8+c)*16 + n]
    int t = threadIdx.x;  // 256
    int cc = blockIdx.x, c = cc >> 3, c2 = cc & 7;
    if (t < S * C) {
        float v[S]; float s = 0.f;
#pragma unroll
        for (int n = 0; n < S; n++) { v[n] = hsig(invh_T[t * S + n]); s += v[n]; }
        float inv = 1.f / s;
#pragma unroll
        for (int n = 0; n < S; n++) Tn[t * S + n] = v[n] * inv;
    }
    __syncthreads();
    int p = t >> 4, n = t & 15;
    float a = 0.f;
#pragma unroll
    for (int k = 0; k < S; k++) a += Tn[(p * 8 + c) * 16 + k] * Tn[(k * 8 + c2) * 16 + n];
    ((unsigned short*)(wsb + WS_TTT))[t * 64 + cc] = f2bf(a);

    if (cc == 0 && t < S) {
        float s = 0.f;
#pragma unroll
        for (int k = 0; k < S; k++) s += hsig(invh_init[k]);
        ((float*)(wsb + WS_INIT))[t] = hsig(invh_init[t]) / s;
        ((float*)(wsb + WS_ACC))[t] = logf(hsig(invh_acc[t]));
    }
}

// Two chunks per block: both global x tiles loaded up-front, TTT B-frags loaded
// once. The ch-1 softmax barrier already orders ch-0's root slot-reads before
// ch-1's construct slot-writes (each wave drains its own LDS reads before any
// barrier), so the loop adds zero barriers.
__global__ void __launch_bounds__(256) chunk_kernel(const float* __restrict__ logx,
                                                    unsigned char* __restrict__ wsb) {
    __shared__ __align__(16) unsigned short slots[32 * SLOT];  // 20736 B
    __shared__ __align__(16) float xs[LC * XSS];               // 2560 B normalized probs
    __shared__ float clpart[4];

    int tid = threadIdx.x, lane = tid & 63, w = tid >> 6;
    int col = lane & 15, quad = lane >> 4;
    int chunk0 = 2 * blockIdx.x, b = blockIdx.y;

    // B-frags for the pair-product construct (wave w owns p-tiles 4w..4w+3).
    const unsigned short* TTT = (const unsigned short*)(wsb + WS_TTT);
    bf16x8 bfr[4][2];
#pragma unroll
    for (int jj = 0; jj < 4; jj++) {
        int t = 4 * w + jj;
#pragma unroll
        for (int kk = 0; kk < 2; kk++)
            bfr[jj][kk] = *(const bf16x8*)(TTT + (t * 16 + col) * 64 + kk * 32 + quad * 8);
    }

    // Both chunks' x tiles: issue global loads now (latency hidden under setup).
    const float* xg = logx + ((size_t)b * L + (size_t)chunk0 * LC) * C;
    float2 vv[2];
    vv[0] = *(const float2*)(xg + 2 * tid);            // coalesced 8 B/lane
    vv[1] = *(const float2*)(xg + LC * C + 2 * tid);

#pragma unroll
    for (int ch = 0; ch < 2; ch++) {
        int chunk = chunk0 + ch;

        // Per-step softmax: thread tid owns channels {2(tid&3), 2(tid&3)+1} of
        // step tid>>2; 4-lane-group shuffle reduce.
        float2 v = vv[ch];
        float m = fmaxf(v.x, v.y);
        m = fmaxf(m, __shfl_xor(m, 1));
        m = fmaxf(m, __shfl_xor(m, 2));
        float e0 = __expf(v.x - m), e1 = __expf(v.y - m);
        float s = e0 + e1;
        s += __shfl_xor(s, 1);
        s += __shfl_xor(s, 2);
        float inv = 1.0f / s;
        *(float2*)(xs + (tid >> 2) * XSS + 2 * (tid & 3)) = make_float2(e0 * inv, e1 * inv);
        float lx = ((tid & 3) == 0) ? (m + __logf(s)) : 0.f;   // one contribution per step
#pragma unroll
        for (int d = 1; d < 64; d <<= 1) lx += __shfl_xor(lx, d);  // wave partial (16 steps)
        if (lane == 0) clpart[w] = lx;
        __syncthreads();
        if (tid == 0)
            ((float*)(wsb + WS_CLOG))[b * K + chunk] = clpart[0] + clpart[1] + clpart[2] + clpart[3];

        // A-frags: y[i][cc'] = xn[2i][c]*xn[2i+1][c'].
        bf16x8 afr[2][2];
#pragma unroll
        for (int mt = 0; mt < 2; mt++) {
            int i2 = 2 * (mt * 16 + col);
            const float2* x1p = (const float2*)(xs + (i2 + 1) * XSS);
            float2 q0 = x1p[0], q1 = x1p[1], q2 = x1p[2], q3 = x1p[3];
#pragma unroll
            for (int kk = 0; kk < 2; kk++) {
                float x0 = xs[i2 * XSS + kk * 4 + quad];
                union { unsigned int u[4]; bf16x8 v8; } cv;
                cv.u[0] = f2bf2(x0 * q0.x, x0 * q0.y);
                cv.u[1] = f2bf2(x0 * q1.x, x0 * q1.y);
                cv.u[2] = f2bf2(x0 * q2.x, x0 * q2.y);
                cv.u[3] = f2bf2(x0 * q3.x, x0 * q3.y);
                afr[mt][kk] = cv.v8;
            }
        }

        // Pair-product construct -> slots 0..31 (parity i&1: even rm / odd cm).
#pragma unroll
        for (int mt = 0; mt < 2; mt++)
#pragma unroll
            for (int jj = 0; jj < 4; jj++) {
                f32x4 acc = {0.f, 0.f, 0.f, 0.f};
#pragma unroll
                for (int kk = 0; kk < 2; kk++)
                    acc = __builtin_amdgcn_mfma_f32_16x16x32_bf16(afr[mt][kk], bfr[jj][kk], acc, 0, 0, 0);
                int t = 4 * w + jj;  // = p
#pragma unroll
                for (int r = 0; r < 4; r++) {
                    int i = mt * 16 + quad * 4 + r;
                    int off = (i & 1) ? (col * RS + t) : (t * RS + col);
                    slots[i * SLOT + off] = f2bf(acc[r]);
                }
            }
        __syncthreads();

        // lv1: wave w owns products i in [4w,4w+4). Even i -> LDS (A of lv2),
        // odd i -> registers (B of lv2, D==B layout).
        bf16x4 B1[2];
        {
            f32x4 z = {0.f, 0.f, 0.f, 0.f};
#pragma unroll
            for (int i2 = 0; i2 < 4; i2++) {
                int i = 4 * w + i2;
                f32x4 d = mfma16(ldfrag4(slots + (2 * i) * SLOT, lane),
                                 ldfrag4(slots + (2 * i + 1) * SLOT, lane), z);
                if (i2 & 1) B1[i2 >> 1] = cvt4(d);
                else store16(slots + (2 * i) * SLOT, d, lane, false);
            }
        }
        f32x4 root = tree_upper(slots, lane, w, B1[0], B1[1]);

        if (w == 0) {
            unsigned short* cp = (unsigned short*)(wsb + WS_CP) + ((size_t)b * K + chunk) * 256;
            if (chunk & 1) {
                ull pk = (ull)f2bf2(root[0], root[1]) | ((ull)f2bf2(root[2], root[3]) << 32);
                *(ull*)(cp + col * 16 + quad * 4) = pk;
            } else {
#pragma unroll
                for (int r = 0; r < 4; r++) cp[(quad * 4 + r) * 16 + col] = f2bf(root[r]);
            }
        }
    }
}

__global__ void __launch_bounds__(256) reduce_kernel(unsigned char* __restrict__ wsb,
                                                     float* __restrict__ out) {
    __shared__ __align__(16) unsigned short slots[32 * SLOT];  // 20736 B
    int tid = threadIdx.x, lane = tid & 63, w = tid >> 6;
    int col = lane & 15, quad = lane >> 4;
    int b = blockIdx.x;

    const unsigned short* cpb = (const unsigned short*)(wsb + WS_CP) + (size_t)b * K * 256;
    // lv0: 32 products of global pairs (even chunk rm -> A, odd cm -> B).
    // Even results -> slot j rm; odd results -> regs (B of lv1).
    bf16x4 B0[4];
    {
        f32x4 z = {0.f, 0.f, 0.f, 0.f};
#pragma unroll
        for (int i2 = 0; i2 < 8; i2++) {
            int j = 8 * w + i2;
            f32x4 d = mfma16(ldfrag_g4(cpb + (size_t)(2 * j) * 256, lane),
                             ldfrag_g4(cpb + (size_t)(2 * j + 1) * 256, lane), z);
            if (i2 & 1) B0[i2 >> 1] = cvt4(d);
            else store16(slots + j * SLOT, d, lane, false);
        }
    }
    bf16x4 B1r[2];
    {
        f32x4 z = {0.f, 0.f, 0.f, 0.f};
#pragma unroll
        for (int i2 = 0; i2 < 4; i2++) {
            int i = 4 * w + i2;  // A = lv0 result 2i @ slot 2i (= 8w + 2*i2)
            f32x4 d = mfma16(ldfrag4(slots + (2 * i) * SLOT, lane), B0[i2], z);
            if (i2 & 1) B1r[i2 >> 1] = cvt4(d);
            else store16(slots + (2 * i) * SLOT, d, lane, false);
        }
    }
    f32x4 troot = tree_upper(slots, lane, w, B1r[0], B1r[1]);

    if (w == 0) {
        const float* initp = (const float*)(wsb + WS_INIT);
        const float* acclog = (const float*)(wsb + WS_ACC);
        float part = 0.f;
#pragma unroll
        for (int r = 0; r < 4; r++) part += initp[quad * 4 + r] * troot[r];
        part += __shfl_xor(part, 16);
        part += __shfl_xor(part, 32);
        float lp = logf(fmaxf(part, 0.f) + 1e-30f) + acclog[col];
        float mx = lp;
#pragma unroll
        for (int d = 1; d < 16; d <<= 1) mx = fmaxf(mx, __shfl_xor(mx, d));
        float a2 = isfinite(mx) ? mx : 0.0f;  // jax.nn.logsumexp semantics
        float sm = expf(lp - a2);
#pragma unroll
        for (int d = 1; d < 16; d <<= 1) sm += __shfl_xor(sm, d);
        float cl = ((const float*)(wsb + WS_CLOG))[b * K + lane];
#pragma unroll
        for (int d = 1; d < 64; d <<= 1) cl += __shfl_xor(cl, d);
        if (lane == 0) out[b] = logf(sm) + a2 + cl;
    }
}

extern "C" void kernel_launch(void* const* d_in, const int* in_sizes, int n_in,
                              void* d_out, int out_size, void* d_ws, size_t ws_size,
                              hipStream_t stream) {
    const float* logx = (const float*)d_in[0];   // (B, L, C) f32
    const float* init = (const float*)d_in[1];   // (S,) f32
    const float* T    = (const float*)d_in[2];   // (S, C, S) f32
    const float* acc  = (const float*)d_in[3];   // (S,) f32
    unsigned char* wsb = (unsigned char*)d_ws;
    float* out = (float*)d_out;

    prepall_kernel<<<64, 256, 0, stream>>>(init, T, acc, wsb);
    chunk_kernel<<<dim3(K / 2, NB), 256, 0, stream>>>(logx, wsb);
    reduce_kernel<<<NB, 256, 0, stream>>>(wsb, out);
}

// Round 4
// 83.257 us; speedup vs baseline: 2.5324x; 1.0048x over previous
//
#include <hip/hip_runtime.h>
#include <hip/hip_bf16.h>
#include <math.h>

#define S 16
#define C 8
#define NB 64   // batch
#define L 4096
#define K 64    // chunks per batch
#define LC 64   // steps per chunk
#define NP 32   // chunk-pairs per batch (in-block combined)

#define SLOT 324  // bf16 elems per matrix slot = 648 B (162 banks % 32 == 2 -> quad-distinct slot bases)
#define RS 20     // row stride in elems (40 B -> conflict-free row-major scatters)
#define XSS 10    // xs floats per step (40 B stride -> 2-way-max bank aliasing on A-frag reads)

typedef __attribute__((ext_vector_type(8))) short bf16x8;
typedef __attribute__((ext_vector_type(4))) short bf16x4;
typedef __attribute__((ext_vector_type(4))) float f32x4;
typedef unsigned long long ull;

// ws byte layout:
#define WS_INIT 0       // f32[16]
#define WS_ACC  64      // f32[16]
#define WS_CLOG 512     // f32[4096] (16 KB)
#define WS_TTT  16896   // bf16 TTT[(p*16+n)][cc'=64] (32 KB), B-frag-ready
#define WS_CP   49664   // bf16 pairP[64*32][256]; even pair row-major, odd [col][row]

__device__ __forceinline__ float hsig(float x) {
    return x / (1.0f + fabsf(x)) * 0.5f + 0.5f;
}
// Native RNE bf16 converts (v_cvt_pk_bf16_f32).
__device__ __forceinline__ unsigned int f2bf2(float a, float b) {
    __hip_bfloat162 h = __float22bfloat162_rn(make_float2(a, b));
    unsigned int u; __builtin_memcpy(&u, &h, 4); return u;
}
__device__ __forceinline__ unsigned short f2bf(float f) {
    __hip_bfloat16 h = __float2bfloat16(f);
    unsigned short u; __builtin_memcpy(&u, &h, 2); return u;
}

// 16x16x16 bf16 MFMA. Fallback: zero-extend BOTH operands with the SAME
// K-permutation into the x32 op — dead products are 0*0, result identical.
__device__ __forceinline__ f32x4 mfma16(bf16x4 a, bf16x4 b, f32x4 c) {
#if __has_builtin(__builtin_amdgcn_mfma_f32_16x16x16bf16_1k)
    return __builtin_amdgcn_mfma_f32_16x16x16bf16_1k(a, b, c, 0, 0, 0);
#else
    bf16x8 a8 = {a[0], a[1], a[2], a[3], 0, 0, 0, 0};
    bf16x8 b8 = {b[0], b[1], b[2], b[3], 0, 0, 0, 0};
    return __builtin_amdgcn_mfma_f32_16x16x32_bf16(a8, b8, c, 0, 0, 0);
#endif
}

// A-frag from a row-major RS-stride slot, or B-frag from a col-major slot:
// both are elems [col*RS + quad*4 .. +3]. 8 B aligned (RS*2=40, SLOT*2=648).
__device__ __forceinline__ bf16x4 ldfrag4(const unsigned short* base, int lane) {
    return *(const bf16x4*)(base + (lane & 15) * RS + (lane >> 4) * 4);
}
// Same from a packed global 16x16 matrix (stride 16).
__device__ __forceinline__ bf16x4 ldfrag_g4(const unsigned short* base, int lane) {
    return *(const bf16x4*)(base + (lane & 15) * 16 + (lane >> 4) * 4);
}
// D-fragment -> B-fragment is the identity lane mapping for 16x16 shapes.
__device__ __forceinline__ bf16x4 cvt4(f32x4 d) {
    union { unsigned int u[2]; bf16x4 v; } cv;
    cv.u[0] = f2bf2(d[0], d[1]);
    cv.u[1] = f2bf2(d[2], d[3]);
    return cv.v;
}
__device__ __forceinline__ void store16(unsigned short* slot, f32x4 d, int lane, bool odd) {
    int col = lane & 15, quad = lane >> 4;
    if (odd) {  // col-major (B-ready): packed 8 B store
        ull pk = (ull)f2bf2(d[0], d[1]) | ((ull)f2bf2(d[2], d[3]) << 32);
        *(ull*)(slot + col * RS + quad * 4) = pk;
    } else {    // row-major (A-ready): 4-elem scatter
#pragma unroll
        for (int r = 0; r < 4; r++) slot[(quad * 4 + r) * RS + col] = f2bf(d[r]);
    }
}

// lv2..root of a 32->1 tree; lv1 even results row-major in LDS at slots 8w and
// 8w+4, lv1 odd results reg-fed (B1a, B1b; D==B layout). ONE barrier; lv4+root
// on wave 0 only (root is only consumed by w0). Waves 1-3 return garbage and
// are free to run ahead — callers must not let them write slots before their
// next __syncthreads (chunk: next softmax barrier; reduce: they exit).
__device__ __forceinline__ f32x4 tree_upper(unsigned short* slots, int lane, int w,
                                            bf16x4 B1a, bf16x4 B1b) {
    f32x4 z = {0.f, 0.f, 0.f, 0.f};
    f32x4 dA = mfma16(ldfrag4(slots + (8 * w) * SLOT, lane), B1a, z);   // lv2 prod 2w
    store16(slots + (8 * w) * SLOT, dA, lane, false);                   // -> A of lv3
    f32x4 dB = mfma16(ldfrag4(slots + (8 * w + 4) * SLOT, lane), B1b, z); // lv2 prod 2w+1
    f32x4 d3 = mfma16(ldfrag4(slots + (8 * w) * SLOT, lane), cvt4(dB), z); // lv3 prod w
    store16(slots + (8 * w) * SLOT, d3, lane, w & 1);  // w0:s0 rm, w1:s8 cm, w2:s16 rm, w3:s24 cm
    __syncthreads();
    f32x4 root = z;
    if (w == 0) {
        f32x4 d4a = mfma16(ldfrag4(slots, lane), ldfrag4(slots + 8 * SLOT, lane), z);
        f32x4 d4b = mfma16(ldfrag4(slots + 16 * SLOT, lane), ldfrag4(slots + 24 * SLOT, lane), z);
        store16(slots, d4a, lane, false);              // rm -> A of root (same-wave, lgkm-ordered)
        root = mfma16(ldfrag4(slots, lane), cvt4(d4b), z);
    }
    return root;
}

// 64 blocks: every block redundantly normalizes T in LDS (cheap), then block cc
// computes TTT[.][cc] = (T_c * T_{c'}) column. Block 0 also writes init/acc.
__global__ void __launch_bounds__(256) prepall_kernel(const float* __restrict__ invh_init,
                                                      const float* __restrict__ invh_T,
                                                      const float* __restrict__ invh_acc,
                                                      unsigned char* __restrict__ wsb) {
    __shared__ float Tn[2048];  // Tn[(p*8+c)*16 + n]
    int t = threadIdx.x;  // 256
    int cc = blockIdx.x, c = cc >> 3, c2 = cc & 7;
    if (t < S * C) {
        float v[S]; float s = 0.f;
#pragma unroll
        for (int n = 0; n < S; n++) { v[n] = hsig(invh_T[t * S + n]); s += v[n]; }
        float inv = 1.f / s;
#pragma unroll
        for (int n = 0; n < S; n++) Tn[t * S + n] = v[n] * inv;
    }
    __syncthreads();
    int p = t >> 4, n = t & 15;
    float a = 0.f;
#pragma unroll
    for (int k = 0; k < S; k++) a += Tn[(p * 8 + c) * 16 + k] * Tn[(k * 8 + c2) * 16 + n];
    ((unsigned short*)(wsb + WS_TTT))[t * 64 + cc] = f2bf(a);

    if (cc == 0 && t < S) {
        float s = 0.f;
#pragma unroll
        for (int k = 0; k < S; k++) s += hsig(invh_init[k]);
        ((float*)(wsb + WS_INIT))[t] = hsig(invh_init[t]) / s;
        ((float*)(wsb + WS_ACC))[t] = logf(hsig(invh_acc[t]));
    }
}

// Two chunks per block, combined in-block to ONE pair matrix (root0 kept in
// VGPRs across ch1). The ch-1 softmax barrier orders ch-0's w0 slot reads
// before ch-1's construct slot-writes, so the loop adds zero barriers.
__global__ void __launch_bounds__(256) chunk_kernel(const float* __restrict__ logx,
                                                    unsigned char* __restrict__ wsb) {
    __shared__ __align__(16) unsigned short slots[32 * SLOT];  // 20736 B
    __shared__ __align__(16) float xs[LC * XSS];               // 2560 B normalized probs
    __shared__ float clpart[4];

    int tid = threadIdx.x, lane = tid & 63, w = tid >> 6;
    int col = lane & 15, quad = lane >> 4;
    int pi = blockIdx.x, b = blockIdx.y;
    int chunk0 = 2 * pi;

    // B-frags for the pair-product construct (wave w owns p-tiles 4w..4w+3).
    const unsigned short* TTT = (const unsigned short*)(wsb + WS_TTT);
    bf16x8 bfr[4][2];
#pragma unroll
    for (int jj = 0; jj < 4; jj++) {
        int t = 4 * w + jj;
#pragma unroll
        for (int kk = 0; kk < 2; kk++)
            bfr[jj][kk] = *(const bf16x8*)(TTT + (t * 16 + col) * 64 + kk * 32 + quad * 8);
    }

    // Both chunks' x tiles: issue global loads now (latency hidden under setup).
    const float* xg = logx + ((size_t)b * L + (size_t)chunk0 * LC) * C;
    float2 vv[2];
    vv[0] = *(const float2*)(xg + 2 * tid);            // coalesced 8 B/lane
    vv[1] = *(const float2*)(xg + LC * C + 2 * tid);

    f32x4 root0, root1;
#pragma unroll
    for (int ch = 0; ch < 2; ch++) {
        int chunk = chunk0 + ch;

        // Per-step softmax: thread tid owns channels {2(tid&3), 2(tid&3)+1} of
        // step tid>>2; 4-lane-group shuffle reduce.
        float2 v = vv[ch];
        float m = fmaxf(v.x, v.y);
        m = fmaxf(m, __shfl_xor(m, 1));
        m = fmaxf(m, __shfl_xor(m, 2));
        float e0 = __expf(v.x - m), e1 = __expf(v.y - m);
        float s = e0 + e1;
        s += __shfl_xor(s, 1);
        s += __shfl_xor(s, 2);
        float inv = 1.0f / s;
        *(float2*)(xs + (tid >> 2) * XSS + 2 * (tid & 3)) = make_float2(e0 * inv, e1 * inv);
        float lx = ((tid & 3) == 0) ? (m + __logf(s)) : 0.f;   // one contribution per step
#pragma unroll
        for (int d = 1; d < 64; d <<= 1) lx += __shfl_xor(lx, d);  // wave partial (16 steps)
        if (lane == 0) clpart[w] = lx;
        __syncthreads();
        if (tid == 0)
            ((float*)(wsb + WS_CLOG))[b * K + chunk] = clpart[0] + clpart[1] + clpart[2] + clpart[3];

        // A-frags: y[i][cc'] = xn[2i][c]*xn[2i+1][c'].
        bf16x8 afr[2][2];
#pragma unroll
        for (int mt = 0; mt < 2; mt++) {
            int i2 = 2 * (mt * 16 + col);
            const float2* x1p = (const float2*)(xs + (i2 + 1) * XSS);
            float2 q0 = x1p[0], q1 = x1p[1], q2 = x1p[2], q3 = x1p[3];
#pragma unroll
            for (int kk = 0; kk < 2; kk++) {
                float x0 = xs[i2 * XSS + kk * 4 + quad];
                union { unsigned int u[4]; bf16x8 v8; } cv;
                cv.u[0] = f2bf2(x0 * q0.x, x0 * q0.y);
                cv.u[1] = f2bf2(x0 * q1.x, x0 * q1.y);
                cv.u[2] = f2bf2(x0 * q2.x, x0 * q2.y);
                cv.u[3] = f2bf2(x0 * q3.x, x0 * q3.y);
                afr[mt][kk] = cv.v8;
            }
        }

        // Pair-product construct -> slots 0..31 (parity i&1: even rm / odd cm).
#pragma unroll
        for (int mt = 0; mt < 2; mt++)
#pragma unroll
            for (int jj = 0; jj < 4; jj++) {
                f32x4 acc = {0.f, 0.f, 0.f, 0.f};
#pragma unroll
                for (int kk = 0; kk < 2; kk++)
                    acc = __builtin_amdgcn_mfma_f32_16x16x32_bf16(afr[mt][kk], bfr[jj][kk], acc, 0, 0, 0);
                int t = 4 * w + jj;  // = p
#pragma unroll
                for (int r = 0; r < 4; r++) {
                    int i = mt * 16 + quad * 4 + r;
                    int off = (i & 1) ? (col * RS + t) : (t * RS + col);
                    slots[i * SLOT + off] = f2bf(acc[r]);
                }
            }
        __syncthreads();

        // lv1: wave w owns products i in [4w,4w+4). Even i -> LDS (A of lv2),
        // odd i -> registers (B of lv2, D==B layout).
        bf16x4 B1[2];
        {
            f32x4 z = {0.f, 0.f, 0.f, 0.f};
#pragma unroll
            for (int i2 = 0; i2 < 4; i2++) {
                int i = 4 * w + i2;
                f32x4 d = mfma16(ldfrag4(slots + (2 * i) * SLOT, lane),
                                 ldfrag4(slots + (2 * i + 1) * SLOT, lane), z);
                if (i2 & 1) B1[i2 >> 1] = cvt4(d);
                else store16(slots + (2 * i) * SLOT, d, lane, false);
            }
        }
        f32x4 root = tree_upper(slots, lane, w, B1[0], B1[1]);  // valid on w0 only
        if (ch == 0) root0 = root; else root1 = root;
    }

    // In-block pair combine (w0 only; waves 1-3 have exited their slot reads).
    if (w == 0) {
        f32x4 z = {0.f, 0.f, 0.f, 0.f};
        store16(slots, root0, lane, false);            // rm -> A (same-wave ordered)
        f32x4 fin = mfma16(ldfrag4(slots, lane), cvt4(root1), z);
        unsigned short* cp = (unsigned short*)(wsb + WS_CP) + ((size_t)b * NP + pi) * 256;
        if (pi & 1) {
            ull pk = (ull)f2bf2(fin[0], fin[1]) | ((ull)f2bf2(fin[2], fin[3]) << 32);
            *(ull*)(cp + col * 16 + quad * 4) = pk;
        } else {
#pragma unroll
            for (int r = 0; r < 4; r++) cp[(quad * 4 + r) * 16 + col] = f2bf(fin[r]);
        }
    }
}

__global__ void __launch_bounds__(256) reduce_kernel(unsigned char* __restrict__ wsb,
                                                     float* __restrict__ out) {
    __shared__ __align__(16) unsigned short slots[32 * SLOT];  // 20736 B
    int tid = threadIdx.x, lane = tid & 63, w = tid >> 6;
    int col = lane & 15, quad = lane >> 4;
    int b = blockIdx.x;

    const unsigned short* cpb = (const unsigned short*)(wsb + WS_CP) + (size_t)b * NP * 256;
    // lv0': 4 products/wave of global pairs (even pair rm -> A, odd cm -> B).
    // Even i2 -> slots 8w, 8w+4 rm; odd i2 -> regs (B of lv2). Feeds tree_upper
    // directly (same contract as chunk's lv1); no barrier needed before it
    // (same-wave write->read is lgkm-ordered).
    bf16x4 B1r[2];
    {
        f32x4 z = {0.f, 0.f, 0.f, 0.f};
#pragma unroll
        for (int i2 = 0; i2 < 4; i2++) {
            int i = 4 * w + i2;
            f32x4 d = mfma16(ldfrag_g4(cpb + (size_t)(2 * i) * 256, lane),
                             ldfrag_g4(cpb + (size_t)(2 * i + 1) * 256, lane), z);
            if (i2 & 1) B1r[i2 >> 1] = cvt4(d);
            else store16(slots + (2 * i) * SLOT, d, lane, false);
        }
    }
    f32x4 troot = tree_upper(slots, lane, w, B1r[0], B1r[1]);

    if (w == 0) {
        const float* initp = (const float*)(wsb + WS_INIT);
        const float* acclog = (const float*)(wsb + WS_ACC);
        float part = 0.f;
#pragma unroll
        for (int r = 0; r < 4; r++) part += initp[quad * 4 + r] * troot[r];
        part += __shfl_xor(part, 16);
        part += __shfl_xor(part, 32);
        float lp = logf(fmaxf(part, 0.f) + 1e-30f) + acclog[col];
        float mx = lp;
#pragma unroll
        for (int d = 1; d < 16; d <<= 1) mx = fmaxf(mx, __shfl_xor(mx, d));
        float a2 = isfinite(mx) ? mx : 0.0f;  // jax.nn.logsumexp semantics
        float sm = expf(lp - a2);
#pragma unroll
        for (int d = 1; d < 16; d <<= 1) sm += __shfl_xor(sm, d);
        float cl = ((const float*)(wsb + WS_CLOG))[b * K + lane];
#pragma unroll
        for (int d = 1; d < 64; d <<= 1) cl += __shfl_xor(cl, d);
        if (lane == 0) out[b] = logf(sm) + a2 + cl;
    }
}

extern "C" void kernel_launch(void* const* d_in, const int* in_sizes, int n_in,
                              void* d_out, int out_size, void* d_ws, size_t ws_size,
                              hipStream_t stream) {
    const float* logx = (const float*)d_in[0];   // (B, L, C) f32
    const float* init = (const float*)d_in[1];   // (S,) f32
    const float* T    = (const float*)d_in[2];   // (S, C, S) f32
    const float* acc  = (const float*)d_in[3];   // (S,) f32
    unsigned char* wsb = (unsigned char*)d_ws;
    float* out = (float*)d_out;

    prepall_kernel<<<64, 256, 0, stream>>>(init, T, acc, wsb);
    chunk_kernel<<<dim3(K / 2, NB), 256, 0, stream>>>(logx, wsb);
    reduce_kernel<<<NB, 256, 0, stream>>>(wsb, out);
}